// Round 1
// baseline (115.840 us; speedup 1.0000x reference)
//
#include <hip/hip_runtime.h>

#define M_DIM 8192
#define N_DIM 8192
#define K_DIM 256

typedef __attribute__((ext_vector_type(4))) int i32x4;

// ---------------- absmax over a 2M-element f32 array -> atomicMax(uint bits) ----------------
__global__ __launch_bounds__(256) void absmax_kernel(const float* __restrict__ x,
                                                     const float* __restrict__ y,
                                                     unsigned int* __restrict__ amax) {
    const float* p = (blockIdx.y == 0) ? x : y;
    const int n4 = (M_DIM * K_DIM) / 4;  // both tensors are 2M elements
    const float4* p4 = (const float4*)p;
    float m = 0.0f;
    int idx = blockIdx.x * blockDim.x + threadIdx.x;
    int stride = gridDim.x * blockDim.x;
    for (int i = idx; i < n4; i += stride) {
        float4 v = p4[i];
        m = fmaxf(m, fmaxf(fmaxf(fabsf(v.x), fabsf(v.y)), fmaxf(fabsf(v.z), fabsf(v.w))));
    }
    // wave (64-lane) reduce
    for (int off = 32; off > 0; off >>= 1)
        m = fmaxf(m, __shfl_down(m, off));
    __shared__ float sm[4];
    int wid = threadIdx.x >> 6;
    if ((threadIdx.x & 63) == 0) sm[wid] = m;
    __syncthreads();
    if (threadIdx.x == 0) {
        m = fmaxf(fmaxf(sm[0], sm[1]), fmaxf(sm[2], sm[3]));
        atomicMax(&amax[blockIdx.y], __float_as_uint(m));  // floats >= 0: uint cmp == float cmp
    }
}

__device__ __forceinline__ float qscale(unsigned int bits) {
    return fmaxf(__uint_as_float(bits) / 127.0f, 1e-12f);
}

__device__ __forceinline__ int quant1(float v, float s) {
    float q = rintf(v / s);                      // RNE matches jnp.round; IEEE div matches t/s
    q = fmaxf(-127.0f, fminf(127.0f, q));
    return (int)q;
}

// ---------------- quantize x: [M][K] f32 -> [M][K] int8, 4 elems/thread ----------------
__global__ __launch_bounds__(256) void quant_x_kernel(const float* __restrict__ x,
                                                      unsigned int* __restrict__ xq_w,
                                                      const unsigned int* __restrict__ amax) {
    const float s = qscale(amax[0]);
    int i = blockIdx.x * blockDim.x + threadIdx.x;  // index in float4 units
    float4 v = ((const float4*)x)[i];
    unsigned b0 = (unsigned)quant1(v.x, s) & 0xFF;
    unsigned b1 = (unsigned)quant1(v.y, s) & 0xFF;
    unsigned b2 = (unsigned)quant1(v.z, s) & 0xFF;
    unsigned b3 = (unsigned)quant1(v.w, s) & 0xFF;
    xq_w[i] = b0 | (b1 << 8) | (b2 << 16) | (b3 << 24);
}

// ---------------- quantize + transpose y: [K][N] f32 -> [N][K] int8 ----------------
// 64x64 tile per block; LDS staging for coalesced transposed writes.
__global__ __launch_bounds__(256) void quant_y_t_kernel(const float* __restrict__ y,
                                                        signed char* __restrict__ yqt,
                                                        const unsigned int* __restrict__ amax) {
    const float s = qscale(amax[1]);
    const int k0 = blockIdx.y * 64;
    const int n0 = blockIdx.x * 64;
    __shared__ signed char tile[64][68];  // +4 pad
    const int t = threadIdx.x;
    #pragma unroll
    for (int r = 0; r < 16; ++r) {
        int idx = r * 256 + t;
        int k = idx >> 6, n = idx & 63;
        float v = y[(size_t)(k0 + k) * N_DIM + n0 + n];
        tile[k][n] = (signed char)quant1(v, s);
    }
    __syncthreads();
    #pragma unroll
    for (int r = 0; r < 4; ++r) {
        int idx = r * 256 + t;
        int n = idx >> 4, kw = idx & 15;
        unsigned w = ((unsigned)(unsigned char)tile[kw * 4 + 0][n])
                   | ((unsigned)(unsigned char)tile[kw * 4 + 1][n] << 8)
                   | ((unsigned)(unsigned char)tile[kw * 4 + 2][n] << 16)
                   | ((unsigned)(unsigned char)tile[kw * 4 + 3][n] << 24);
        *(unsigned*)(yqt + (size_t)(n0 + n) * K_DIM + k0 + kw * 4) = w;
    }
}

// ---------------- int8 MFMA GEMM: 128x128 tile/block, 4 waves of 64x64 ----------------
// Operands are 2MB each (L2/L3 resident) -> load fragments straight from global, no LDS.
__global__ __launch_bounds__(256) void gemm_i8_kernel(const signed char* __restrict__ xq,
                                                      const signed char* __restrict__ yqt,
                                                      const unsigned int* __restrict__ amax,
                                                      float* __restrict__ out) {
    const int tid = threadIdx.x;
    const int wid = tid >> 6;
    const int lane = tid & 63;
    const int wr = wid >> 1, wc = wid & 1;
    const int row0 = blockIdx.y * 128 + wr * 64;
    const int col0 = blockIdx.x * 128 + wc * 64;

    const int lrow = lane & 15;            // fragment row (A) / col (B) within 16
    const int lk = (lane >> 4) * 16;       // fragment k offset: 0,16,32,48

    const signed char* aptr = xq + (size_t)(row0 + lrow) * K_DIM + lk;
    const signed char* bptr = yqt + (size_t)(col0 + lrow) * K_DIM + lk;

    i32x4 acc[4][4] = {};
    #pragma unroll
    for (int ks = 0; ks < 4; ++ks) {       // K = 4 * 64
        i32x4 a[4], b[4];
        #pragma unroll
        for (int m = 0; m < 4; ++m)
            a[m] = *(const i32x4*)(aptr + (size_t)(m * 16) * K_DIM + ks * 64);
        #pragma unroll
        for (int n = 0; n < 4; ++n)
            b[n] = *(const i32x4*)(bptr + (size_t)(n * 16) * K_DIM + ks * 64);
        #pragma unroll
        for (int m = 0; m < 4; ++m)
            #pragma unroll
            for (int n = 0; n < 4; ++n)
                acc[m][n] = __builtin_amdgcn_mfma_i32_16x16x64_i8(a[m], b[n], acc[m][n], 0, 0, 0);
    }

    // dequant scale, computed exactly in the reference's order
    const float sx = qscale(amax[0]);
    const float sy = qscale(amax[1]);
    const float scale = (sx * 1024.0f) * (sy / 1024.0f);

    // C/D layout (16x16, dtype-independent): col = lane&15, row = (lane>>4)*4 + reg
    const int orow = row0 + (lane >> 4) * 4;
    const int ocol = col0 + (lane & 15);
    #pragma unroll
    for (int m = 0; m < 4; ++m)
        #pragma unroll
        for (int n = 0; n < 4; ++n)
            #pragma unroll
            for (int r = 0; r < 4; ++r)
                out[(size_t)(orow + m * 16 + r) * N_DIM + ocol + n * 16] =
                    (float)acc[m][n][r] * scale;
}

extern "C" void kernel_launch(void* const* d_in, const int* in_sizes, int n_in,
                              void* d_out, int out_size, void* d_ws, size_t ws_size,
                              hipStream_t stream) {
    const float* x = (const float*)d_in[0];   // [8192, 256]
    const float* y = (const float*)d_in[1];   // [256, 8192]
    float* out = (float*)d_out;               // [8192, 8192]

    unsigned char* ws = (unsigned char*)d_ws;
    unsigned int* amax = (unsigned int*)ws;                       // 2 slots
    signed char* xq = (signed char*)(ws + 1024);                  // 2 MB
    signed char* yqt = xq + (size_t)M_DIM * K_DIM;                // 2 MB

    // zero the absmax slots (harness does not re-poison between replays)
    hipMemsetAsync(d_ws, 0, 1024, stream);

    absmax_kernel<<<dim3(1024, 2), 256, 0, stream>>>(x, y, amax);

    quant_x_kernel<<<(M_DIM * K_DIM / 4) / 256, 256, 0, stream>>>(x, (unsigned int*)xq, amax);

    quant_y_t_kernel<<<dim3(N_DIM / 64, K_DIM / 64), 256, 0, stream>>>(y, yqt, amax);

    gemm_i8_kernel<<<dim3(N_DIM / 128, M_DIM / 128), 256, 0, stream>>>(xq, yqt, amax, out);
}

// Round 3
// 95.548 us; speedup vs baseline: 1.2124x; 1.2124x over previous
//
#include <hip/hip_runtime.h>

#define M_DIM 8192
#define N_DIM 8192
#define K_DIM 256

typedef __attribute__((ext_vector_type(4))) int i32x4;
typedef __attribute__((ext_vector_type(4))) float f32x4;

// ---------------- absmax over a 2M-element f32 array -> atomicMax(uint bits) ----------------
__global__ __launch_bounds__(256) void absmax_kernel(const float* __restrict__ x,
                                                     const float* __restrict__ y,
                                                     unsigned int* __restrict__ amax) {
    const float* p = (blockIdx.y == 0) ? x : y;
    const int n4 = (M_DIM * K_DIM) / 4;  // both tensors are 2M elements
    const float4* p4 = (const float4*)p;
    float m = 0.0f;
    int idx = blockIdx.x * blockDim.x + threadIdx.x;
    int stride = gridDim.x * blockDim.x;   // 256 blocks * 256 thr -> 8 iters
    for (int i = idx; i < n4; i += stride) {
        float4 v = p4[i];
        m = fmaxf(m, fmaxf(fmaxf(fabsf(v.x), fabsf(v.y)), fmaxf(fabsf(v.z), fabsf(v.w))));
    }
    for (int off = 32; off > 0; off >>= 1)
        m = fmaxf(m, __shfl_down(m, off));
    __shared__ float sm[4];
    int wid = threadIdx.x >> 6;
    if ((threadIdx.x & 63) == 0) sm[wid] = m;
    __syncthreads();
    if (threadIdx.x == 0) {
        m = fmaxf(fmaxf(sm[0], sm[1]), fmaxf(sm[2], sm[3]));
        atomicMax(&amax[blockIdx.y], __float_as_uint(m));  // floats >= 0: uint cmp == float cmp
    }
}

__device__ __forceinline__ float qscale(unsigned int bits) {
    return fmaxf(__uint_as_float(bits) / 127.0f, 1e-12f);
}

__device__ __forceinline__ int quant1(float v, float s) {
    float q = rintf(v / s);                      // RNE matches jnp.round; IEEE div matches t/s
    q = fmaxf(-127.0f, fminf(127.0f, q));
    return (int)q;
}

// ---------------- quantize x: [M][K] f32 -> [M][K] int8, 4 elems/thread ----------------
__global__ __launch_bounds__(256) void quant_x_kernel(const float* __restrict__ x,
                                                      unsigned int* __restrict__ xq_w,
                                                      const unsigned int* __restrict__ amax) {
    const float s = qscale(amax[0]);
    int i = blockIdx.x * blockDim.x + threadIdx.x;  // index in float4 units
    float4 v = ((const float4*)x)[i];
    unsigned b0 = (unsigned)quant1(v.x, s) & 0xFF;
    unsigned b1 = (unsigned)quant1(v.y, s) & 0xFF;
    unsigned b2 = (unsigned)quant1(v.z, s) & 0xFF;
    unsigned b3 = (unsigned)quant1(v.w, s) & 0xFF;
    xq_w[i] = b0 | (b1 << 8) | (b2 << 16) | (b3 << 24);
}

// ---------------- quantize + transpose y: [K][N] f32 -> [N][K] int8 ----------------
__global__ __launch_bounds__(256) void quant_y_t_kernel(const float* __restrict__ y,
                                                        signed char* __restrict__ yqt,
                                                        const unsigned int* __restrict__ amax) {
    const float s = qscale(amax[1]);
    const int k0 = blockIdx.y * 64;
    const int n0 = blockIdx.x * 64;
    __shared__ signed char tile[64][68];  // +4 pad
    const int t = threadIdx.x;
    #pragma unroll
    for (int r = 0; r < 16; ++r) {
        int idx = r * 256 + t;
        int k = idx >> 6, n = idx & 63;
        float v = y[(size_t)(k0 + k) * N_DIM + n0 + n];
        tile[k][n] = (signed char)quant1(v, s);
    }
    __syncthreads();
    #pragma unroll
    for (int r = 0; r < 4; ++r) {
        int idx = r * 256 + t;
        int n = idx >> 4, kw = idx & 15;
        unsigned w = ((unsigned)(unsigned char)tile[kw * 4 + 0][n])
                   | ((unsigned)(unsigned char)tile[kw * 4 + 1][n] << 8)
                   | ((unsigned)(unsigned char)tile[kw * 4 + 2][n] << 16)
                   | ((unsigned)(unsigned char)tile[kw * 4 + 3][n] << 24);
        *(unsigned*)(yqt + (size_t)(n0 + n) * K_DIM + k0 + kw * 4) = w;
    }
}

// ---------------- int8 MFMA GEMM: 128x128 tile/block, 4 waves of 64x64 ----------------
// Operands (4MB total) are L2-resident -> fragments straight from global, no LDS staging.
// Epilogue: stage C through LDS in 4 chunks -> fully-coalesced non-temporal float4 stores.
__global__ __launch_bounds__(256) void gemm_i8_kernel(const signed char* __restrict__ xq,
                                                      const signed char* __restrict__ yqt,
                                                      const unsigned int* __restrict__ amax,
                                                      float* __restrict__ out) {
    const int tid = threadIdx.x;
    const int wid = tid >> 6;
    const int lane = tid & 63;
    const int wr = wid >> 1, wc = wid & 1;
    const int row0 = blockIdx.y * 128 + wr * 64;
    const int col0 = blockIdx.x * 128 + wc * 64;

    const int lrow = lane & 15;            // fragment outer index within 16
    const int lk = (lane >> 4) * 16;       // fragment k offset: 0,16,32,48

    const signed char* aptr = xq + (size_t)(row0 + lrow) * K_DIM + lk;
    const signed char* bptr = yqt + (size_t)(col0 + lrow) * K_DIM + lk;

    i32x4 acc[4][4] = {};
    #pragma unroll
    for (int ks = 0; ks < 4; ++ks) {       // K = 4 * 64
        i32x4 a[4], b[4];
        #pragma unroll
        for (int m = 0; m < 4; ++m)
            a[m] = *(const i32x4*)(aptr + (size_t)(m * 16) * K_DIM + ks * 64);
        #pragma unroll
        for (int n = 0; n < 4; ++n)
            b[n] = *(const i32x4*)(bptr + (size_t)(n * 16) * K_DIM + ks * 64);
        #pragma unroll
        for (int m = 0; m < 4; ++m)
            #pragma unroll
            for (int n = 0; n < 4; ++n)
                acc[m][n] = __builtin_amdgcn_mfma_i32_16x16x64_i8(a[m], b[n], acc[m][n], 0, 0, 0);
    }

    const float sx = qscale(amax[0]);
    const float sy = qscale(amax[1]);
    const float scale = (sx * 1024.0f) * (sy / 1024.0f);

    // ---- LDS-staged epilogue: 4 chunks of 32 rows x 128 cols (16.9KB) ----
    // MFMA C/D layout (16x16): col = lane&15, row = (lane>>4)*4 + r
    __shared__ float lds[32][132];  // stride 132: row r, col c -> bank (4r+c)%32, <=2-way (free)
    const int qrow = (lane >> 4) * 4;      // 0,4,8,12
    const int qcol = lane & 15;

    #pragma unroll
    for (int m = 0; m < 4; ++m) {
        __syncthreads();                   // protect LDS reuse from previous chunk
        #pragma unroll
        for (int n = 0; n < 4; ++n)
            #pragma unroll
            for (int r = 0; r < 4; ++r)
                lds[wr * 16 + qrow + r][wc * 64 + n * 16 + qcol] =
                    (float)acc[m][n][r] * scale;
        __syncthreads();
        // block-wide coalesced write-out: 32 rows x 512B, 1KB per wave instruction
        #pragma unroll
        for (int i = 0; i < 4; ++i) {
            int row = i * 8 + (tid >> 5);          // 0..31 (wave-relative sub-rows)
            int col4 = tid & 31;                   // float4 column index 0..31
            f32x4 v = *(const f32x4*)&lds[row][col4 * 4];
            int grow = blockIdx.y * 128 + (row >> 4) * 64 + m * 16 + (row & 15);
            int gcol = blockIdx.x * 128 + col4 * 4;
            __builtin_nontemporal_store(v, (f32x4*)&out[(size_t)grow * N_DIM + gcol]);
        }
    }
}

extern "C" void kernel_launch(void* const* d_in, const int* in_sizes, int n_in,
                              void* d_out, int out_size, void* d_ws, size_t ws_size,
                              hipStream_t stream) {
    const float* x = (const float*)d_in[0];   // [8192, 256]
    const float* y = (const float*)d_in[1];   // [256, 8192]
    float* out = (float*)d_out;               // [8192, 8192]

    unsigned char* ws = (unsigned char*)d_ws;
    unsigned int* amax = (unsigned int*)ws;                       // 2 slots
    signed char* xq = (signed char*)(ws + 1024);                  // 2 MB
    signed char* yqt = xq + (size_t)M_DIM * K_DIM;                // 2 MB

    // zero the absmax slots (harness does not re-poison between replays)
    (void)hipMemsetAsync(d_ws, 0, 1024, stream);

    absmax_kernel<<<dim3(256, 2), 256, 0, stream>>>(x, y, amax);

    quant_x_kernel<<<(M_DIM * K_DIM / 4) / 256, 256, 0, stream>>>(x, (unsigned int*)xq, amax);

    quant_y_t_kernel<<<dim3(N_DIM / 64, K_DIM / 64), 256, 0, stream>>>(y, yqt, amax);

    gemm_i8_kernel<<<dim3(N_DIM / 128, M_DIM / 128), 256, 0, stream>>>(xq, yqt, amax, out);
}

// Round 4
// 92.682 us; speedup vs baseline: 1.2499x; 1.0309x over previous
//
#include <hip/hip_runtime.h>

#define M_DIM 8192
#define N_DIM 8192
#define K_DIM 256

typedef __attribute__((ext_vector_type(4))) int i32x4;
typedef __attribute__((ext_vector_type(4))) float f32x4;

// Raw workgroup barrier that waits only on LDS ops (lgkmcnt), NOT on outstanding
// global stores (vmcnt). __syncthreads would drain vmcnt(0) -> serializes the
// store pipeline every chunk. Cross-wave hazard here is LDS-only, so this is safe.
__device__ __forceinline__ void bar_lds() {
    asm volatile("s_waitcnt lgkmcnt(0)" ::: "memory");
    __builtin_amdgcn_sched_barrier(0);   // rule #18: pin ops around inline-asm waitcnt
    __builtin_amdgcn_s_barrier();
}

// ---------------- absmax over x and y -> atomicMax(uint bits) ----------------
__global__ __launch_bounds__(256) void absmax_kernel(const float* __restrict__ x,
                                                     const float* __restrict__ y,
                                                     unsigned int* __restrict__ amax) {
    const float* p = (blockIdx.y == 0) ? x : y;
    const int n4 = (M_DIM * K_DIM) / 4;
    const float4* p4 = (const float4*)p;
    float m = 0.0f;
    int idx = blockIdx.x * blockDim.x + threadIdx.x;
    int stride = gridDim.x * blockDim.x;
    for (int i = idx; i < n4; i += stride) {
        float4 v = p4[i];
        m = fmaxf(m, fmaxf(fmaxf(fabsf(v.x), fabsf(v.y)), fmaxf(fabsf(v.z), fabsf(v.w))));
    }
    for (int off = 32; off > 0; off >>= 1)
        m = fmaxf(m, __shfl_down(m, off));
    __shared__ float sm[4];
    int wid = threadIdx.x >> 6;
    if ((threadIdx.x & 63) == 0) sm[wid] = m;
    __syncthreads();
    if (threadIdx.x == 0) {
        m = fmaxf(fmaxf(sm[0], sm[1]), fmaxf(sm[2], sm[3]));
        atomicMax(&amax[blockIdx.y], __float_as_uint(m));  // floats >= 0: uint cmp == float cmp
    }
}

__device__ __forceinline__ float qscale(unsigned int bits) {
    return fmaxf(__uint_as_float(bits) / 127.0f, 1e-12f);
}

__device__ __forceinline__ int quant1(float v, float s) {
    float q = rintf(v / s);                      // RNE matches jnp.round; IEEE div matches t/s
    q = fmaxf(-127.0f, fminf(127.0f, q));
    return (int)q;
}

// ---------------- fused quantize: x -> xq [M][K], y -> yqt [N][K] (transposed) ----------------
// blocks [0, 2048): x path, 4 elems/thread. blocks [2048, 2560): y 64x64 transpose tiles.
__global__ __launch_bounds__(256) void quant_kernel(const float* __restrict__ x,
                                                    const float* __restrict__ y,
                                                    unsigned int* __restrict__ xq_w,
                                                    signed char* __restrict__ yqt,
                                                    const unsigned int* __restrict__ amax) {
    __shared__ signed char tile[64][68];  // +4 pad (y path only)
    int b = blockIdx.x;
    const int t = threadIdx.x;
    if (b < 2048) {
        const float s = qscale(amax[0]);
        int i = b * 256 + t;  // float4 index
        float4 v = ((const float4*)x)[i];
        unsigned b0 = (unsigned)quant1(v.x, s) & 0xFF;
        unsigned b1 = (unsigned)quant1(v.y, s) & 0xFF;
        unsigned b2 = (unsigned)quant1(v.z, s) & 0xFF;
        unsigned b3 = (unsigned)quant1(v.w, s) & 0xFF;
        xq_w[i] = b0 | (b1 << 8) | (b2 << 16) | (b3 << 24);
    } else {
        b -= 2048;
        const float s = qscale(amax[1]);
        const int n0 = (b & 127) * 64;
        const int k0 = (b >> 7) * 64;
        #pragma unroll
        for (int r = 0; r < 16; ++r) {
            int idx = r * 256 + t;
            int k = idx >> 6, n = idx & 63;
            float v = y[(size_t)(k0 + k) * N_DIM + n0 + n];
            tile[k][n] = (signed char)quant1(v, s);
        }
        __syncthreads();
        #pragma unroll
        for (int r = 0; r < 4; ++r) {
            int idx = r * 256 + t;
            int n = idx >> 4, kw = idx & 15;
            unsigned w = ((unsigned)(unsigned char)tile[kw * 4 + 0][n])
                       | ((unsigned)(unsigned char)tile[kw * 4 + 1][n] << 8)
                       | ((unsigned)(unsigned char)tile[kw * 4 + 2][n] << 16)
                       | ((unsigned)(unsigned char)tile[kw * 4 + 3][n] << 24);
            *(unsigned*)(yqt + (size_t)(n0 + n) * K_DIM + k0 + kw * 4) = w;
        }
    }
}

// ---------------- int8 MFMA GEMM: 128x128 tile/block, 4 waves of 64x64 ----------------
// Operands (4MB total) are L2-resident -> fragments straight from global, no LDS staging.
// Epilogue: LDS-staged coalesced nt stores; raw lgkm-only barriers keep all global
// stores in flight across chunks (no vmcnt drain until s_endpgm).
__global__ __launch_bounds__(256) void gemm_i8_kernel(const signed char* __restrict__ xq,
                                                      const signed char* __restrict__ yqt,
                                                      const unsigned int* __restrict__ amax,
                                                      float* __restrict__ out) {
    const int tid = threadIdx.x;
    const int wid = tid >> 6;
    const int lane = tid & 63;
    const int wr = wid >> 1, wc = wid & 1;
    const int row0 = blockIdx.y * 128 + wr * 64;
    const int col0 = blockIdx.x * 128 + wc * 64;

    const int lrow = lane & 15;            // fragment outer index within 16
    const int lk = (lane >> 4) * 16;       // fragment k offset: 0,16,32,48

    const signed char* aptr = xq + (size_t)(row0 + lrow) * K_DIM + lk;
    const signed char* bptr = yqt + (size_t)(col0 + lrow) * K_DIM + lk;

    i32x4 acc[4][4] = {};
    #pragma unroll
    for (int ks = 0; ks < 4; ++ks) {       // K = 4 * 64
        i32x4 a[4], b[4];
        #pragma unroll
        for (int m = 0; m < 4; ++m)
            a[m] = *(const i32x4*)(aptr + (size_t)(m * 16) * K_DIM + ks * 64);
        #pragma unroll
        for (int n = 0; n < 4; ++n)
            b[n] = *(const i32x4*)(bptr + (size_t)(n * 16) * K_DIM + ks * 64);
        #pragma unroll
        for (int m = 0; m < 4; ++m)
            #pragma unroll
            for (int n = 0; n < 4; ++n)
                acc[m][n] = __builtin_amdgcn_mfma_i32_16x16x64_i8(a[m], b[n], acc[m][n], 0, 0, 0);
    }

    const float sx = qscale(amax[0]);
    const float sy = qscale(amax[1]);
    const float scale = (sx * 1024.0f) * (sy / 1024.0f);

    // ---- LDS-staged epilogue: 4 chunks of 32 rows x 128 cols ----
    // MFMA C/D layout (16x16): col = lane&15, row = (lane>>4)*4 + r
    __shared__ float lds[32][132];  // write phase <=2-way bank alias (free)
    const int qrow = (lane >> 4) * 4;
    const int qcol = lane & 15;

    #pragma unroll
    for (int m = 0; m < 4; ++m) {
        if (m) bar_lds();                  // prior chunk's LDS reads done (lgkm only)
        #pragma unroll
        for (int n = 0; n < 4; ++n)
            #pragma unroll
            for (int r = 0; r < 4; ++r)
                lds[wr * 16 + qrow + r][wc * 64 + n * 16 + qcol] =
                    (float)acc[m][n][r] * scale;
        bar_lds();                         // writes visible (lgkm only, stores stay in flight)
        // block-wide coalesced write-out: 2 rows x 512B per wave instruction
        #pragma unroll
        for (int i = 0; i < 4; ++i) {
            int row = i * 8 + (tid >> 5);
            int col4 = tid & 31;
            f32x4 v = *(const f32x4*)&lds[row][col4 * 4];
            int grow = blockIdx.y * 128 + (row >> 4) * 64 + m * 16 + (row & 15);
            int gcol = blockIdx.x * 128 + col4 * 4;
            __builtin_nontemporal_store(v, (f32x4*)&out[(size_t)grow * N_DIM + gcol]);
        }
    }
}

extern "C" void kernel_launch(void* const* d_in, const int* in_sizes, int n_in,
                              void* d_out, int out_size, void* d_ws, size_t ws_size,
                              hipStream_t stream) {
    const float* x = (const float*)d_in[0];   // [8192, 256]
    const float* y = (const float*)d_in[1];   // [256, 8192]
    float* out = (float*)d_out;               // [8192, 8192]

    unsigned char* ws = (unsigned char*)d_ws;
    unsigned int* amax = (unsigned int*)ws;                       // 2 slots
    signed char* xq = (signed char*)(ws + 1024);                  // 2 MB
    signed char* yqt = xq + (size_t)M_DIM * K_DIM;                // 2 MB

    // zero the absmax slots (0xAA poison reads as huge uint -> must clear each call)
    (void)hipMemsetAsync(d_ws, 0, 1024, stream);

    absmax_kernel<<<dim3(256, 2), 256, 0, stream>>>(x, y, amax);

    quant_kernel<<<2048 + 512, 256, 0, stream>>>(x, y, (unsigned int*)xq, yqt, amax);

    gemm_i8_kernel<<<dim3(N_DIM / 128, M_DIM / 128), 256, 0, stream>>>(xq, yqt, amax, out);
}